// Round 12
// baseline (364.187 us; speedup 1.0000x reference)
//
#include <hip/hip_runtime.h>
#include <stdint.h>

#define N_NODES 50000
#define N_EDGES 800000
#define D_IN 128
#define H1 96
#define H2 64
#define GEMM_NODES 32
#define GEMM_BLOCKS ((N_NODES + GEMM_NODES - 1) / GEMM_NODES)  // 1563
#define COUNT_BLOCKS 512
#define SCAN_BLK 256
#define N_SBLK ((N_NODES + SCAN_BLK - 1) / SCAN_BLK)   // 196
#define SCAT_BLOCKS 2048
#define AGG_BLOCKS 2048
#define N_THIRD 16667   // ceil(50000/3)

// =============== K1: gemm hs = (x@W1)*... wait dinv not ready yet ===============
// NOTE: dinv is NOT available at K1 time (needs count+scan). So gemm writes
// UNSCALED h, and the dinv scale is folded into agg (multiply acc by dinv[s]?
// No -- norm is dinv[src]*dinv[dst]; the src factor must be in hs).
// Instead: gemm arm here writes h = x@W1 (unscaled); K3's spare arm applies
// h *= dinv (R7-validated split).
__global__ __launch_bounds__(256) void k1_gemm_count(const float* __restrict__ x,
                                                     const float* __restrict__ W1,
                                                     float* __restrict__ h,
                                                     const int* __restrict__ dst,
                                                     int* __restrict__ deg) {
    __shared__ float sx[GEMM_NODES * D_IN];  // 16 KB
    int tid = threadIdx.x;

    if (blockIdx.x < GEMM_BLOCKS) {
        int base = blockIdx.x * GEMM_NODES;
        const float4* x4 = (const float4*)x;
        for (int i = tid; i < GEMM_NODES * D_IN / 4; i += 256) {
            int n = base + i / (D_IN / 4);
            if (n < N_NODES) ((float4*)sx)[i] = x4[(size_t)base * (D_IN / 4) + i];
        }
        __syncthreads();

        int fg = tid & 31;
        int ng = tid >> 5;

        float acc[4][3];
#pragma unroll
        for (int i = 0; i < 4; ++i)
#pragma unroll
            for (int j = 0; j < 3; ++j) acc[i][j] = 0.0f;

#pragma unroll 4
        for (int k = 0; k < D_IN; ++k) {
            float w0 = W1[k * H1 + fg];
            float w1 = W1[k * H1 + fg + 32];
            float w2 = W1[k * H1 + fg + 64];
#pragma unroll
            for (int i = 0; i < 4; ++i) {
                float xv = sx[(ng * 4 + i) * D_IN + k];
                acc[i][0] = fmaf(xv, w0, acc[i][0]);
                acc[i][1] = fmaf(xv, w1, acc[i][1]);
                acc[i][2] = fmaf(xv, w2, acc[i][2]);
            }
        }

#pragma unroll
        for (int i = 0; i < 4; ++i) {
            int n = base + ng * 4 + i;
            if (n < N_NODES) {
                h[(size_t)n * H1 + fg]      = acc[i][0];
                h[(size_t)n * H1 + fg + 32] = acc[i][1];
                h[(size_t)n * H1 + fg + 64] = acc[i][2];
            }
        }
    } else {
        int bid = blockIdx.x - GEMM_BLOCKS;
        int gid = bid * 256 + tid;
        int stride = COUNT_BLOCKS * 256;
        const int4* d4 = (const int4*)dst;
        for (int i = gid; i < N_EDGES / 4; i += stride) {
            int4 d = d4[i];
            atomicAdd(&deg[d.x], 1);
            atomicAdd(&deg[d.y], 1);
            atomicAdd(&deg[d.z], 1);
            atomicAdd(&deg[d.w], 1);
        }
    }
}

// ---------------- 3-phase device-wide exclusive scan ----------------
__global__ __launch_bounds__(SCAN_BLK) void deg_part_kernel(const int* __restrict__ deg,
                                                            int* __restrict__ block_sums) {
    __shared__ int s[SCAN_BLK];
    int t = threadIdx.x;
    int i = blockIdx.x * SCAN_BLK + t;
    s[t] = (i < N_NODES) ? deg[i] : 0;
    __syncthreads();
    for (int off = SCAN_BLK / 2; off > 0; off >>= 1) {
        if (t < off) s[t] += s[t + off];
        __syncthreads();
    }
    if (t == 0) block_sums[blockIdx.x] = s[0];
}

__global__ __launch_bounds__(SCAN_BLK) void block_scan_kernel(int* __restrict__ block_sums) {
    __shared__ int s[SCAN_BLK];
    int t = threadIdx.x;
    int v = (t < N_SBLK) ? block_sums[t] : 0;
    s[t] = v;
    __syncthreads();
    for (int off = 1; off < SCAN_BLK; off <<= 1) {
        int u = (t >= off) ? s[t - off] : 0;
        __syncthreads();
        s[t] += u;
        __syncthreads();
    }
    if (t < N_SBLK) block_sums[t] = s[t] - v;  // exclusive
}

__global__ __launch_bounds__(SCAN_BLK) void deg_scan_kernel(const int* __restrict__ deg,
                                                            const int* __restrict__ block_off,
                                                            int* __restrict__ row_start,
                                                            int* __restrict__ cursor,
                                                            float* __restrict__ dinv) {
    __shared__ int s[SCAN_BLK];
    int t = threadIdx.x;
    int i = blockIdx.x * SCAN_BLK + t;
    int v = (i < N_NODES) ? deg[i] : 0;
    s[t] = v;
    __syncthreads();
    for (int off = 1; off < SCAN_BLK; off <<= 1) {
        int u = (t >= off) ? s[t - off] : 0;
        __syncthreads();
        s[t] += u;
        __syncthreads();
    }
    int excl = s[t] - v + block_off[blockIdx.x];
    if (i < N_NODES) {
        row_start[i] = excl;
        cursor[i] = excl;
        dinv[i] = rsqrtf((float)v + 1.0f);  // +1 self-loop
    }
    if (i == 0) row_start[N_NODES] = N_EDGES;
}

// =============== K3: scatter (CSR, int4-vectorized)  ||  h *= dinv[row] ===============
__global__ __launch_bounds__(256) void k3_scatter_scale(const int* __restrict__ src,
                                                        const int* __restrict__ dst,
                                                        int* __restrict__ cursor,
                                                        int* __restrict__ sorted_src,
                                                        float* __restrict__ h,
                                                        const float* __restrict__ dinv) {
    int tid = threadIdx.x;
    if (blockIdx.x < SCAT_BLOCKS) {
        int gid = blockIdx.x * 256 + tid;
        int stride = SCAT_BLOCKS * 256;
        const int4* s4p = (const int4*)src;
        const int4* d4p = (const int4*)dst;
        for (int i = gid; i < N_EDGES / 4; i += stride) {
            int4 sv = s4p[i];
            int4 dv = d4p[i];
            int p0 = atomicAdd(&cursor[dv.x], 1);
            int p1 = atomicAdd(&cursor[dv.y], 1);
            int p2 = atomicAdd(&cursor[dv.z], 1);
            int p3 = atomicAdd(&cursor[dv.w], 1);
            __builtin_nontemporal_store(sv.x, &sorted_src[p0]);
            __builtin_nontemporal_store(sv.y, &sorted_src[p1]);
            __builtin_nontemporal_store(sv.z, &sorted_src[p2]);
            __builtin_nontemporal_store(sv.w, &sorted_src[p3]);
        }
    } else {
        // scale arm: 50000*96 floats = 1.2M float4
        int bid = blockIdx.x - SCAT_BLOCKS;
        int gid = bid * 256 + tid;
        int stride = 512 * 256;
        float4* h4 = (float4*)h;
        const int TOT = N_NODES * (H1 / 4);  // 1,200,000
        for (int i = gid; i < TOT; i += stride) {
            int n = i / (H1 / 4);
            float dv = dinv[n];
            float4 v = h4[i];
            v.x *= dv; v.y *= dv; v.z *= dv; v.w *= dv;
            h4[i] = v;
        }
    }
}

// ---------------- fused pull-aggregate + ReLU + sum-pool (R3-exact loop, node range) ----------------
__global__ __launch_bounds__(256) void agg_pool_kernel(const float* __restrict__ hs,
                                                       const int* __restrict__ row_start,
                                                       const int* __restrict__ sorted_src,
                                                       const float* __restrict__ dinv,
                                                       const float* __restrict__ b1,
                                                       float* __restrict__ g,
                                                       int n0, int n1) {
    int tid = threadIdx.x;
    int grp = tid >> 7;
    int f = tid & 127;
    bool act = f < H1;
    float bf = act ? b1[f] : 0.0f;
    float gacc = 0.0f;

    for (int n = n0 + blockIdx.x * 2 + grp; n < n1; n += gridDim.x * 2) {
        float acc = act ? hs[(size_t)n * H1 + f] : 0.0f;  // self-loop term
        int e = row_start[n];
        int eend = row_start[n + 1];
        for (; e + 4 <= eend; e += 4) {
            int s0 = sorted_src[e];
            int s1 = sorted_src[e + 1];
            int s2 = sorted_src[e + 2];
            int s3 = sorted_src[e + 3];
            if (act) {
                float v0 = hs[(size_t)s0 * H1 + f];
                float v1 = hs[(size_t)s1 * H1 + f];
                float v2 = hs[(size_t)s2 * H1 + f];
                float v3 = hs[(size_t)s3 * H1 + f];
                acc += (v0 + v1) + (v2 + v3);
            }
        }
        for (; e < eend; ++e) {
            int s = sorted_src[e];
            if (act) acc += hs[(size_t)s * H1 + f];
        }
        if (act) gacc += fmaxf(fmaf(dinv[n], acc, bf), 0.0f);
    }

    __shared__ float sg[H1];
    if (grp == 0 && act) sg[f] = gacc;
    __syncthreads();
    if (grp == 1 && act) atomicAdd(&sg[f], gacc);
    __syncthreads();
    if (grp == 0 && act) atomicAdd(&g[f], sg[f]);
}

// ---------------- tiny MLP head (weights staged in LDS, coalesced) ----------------
__global__ __launch_bounds__(256) void mlp_kernel(const float* __restrict__ g,
                           const float* __restrict__ lw1, const float* __restrict__ lb1,
                           const float* __restrict__ lw2, const float* __restrict__ lb2,
                           const float* __restrict__ lw3, const float* __restrict__ lb3,
                           float* __restrict__ out) {
    __shared__ float slw1[H1 * H1];  // 36 KB
    __shared__ float slw2[H1 * H2];  // 24 KB
    __shared__ float slw3[H2];
    __shared__ float sg[H1], v1[H1], v2[H2];
    int t = threadIdx.x;  // 256 threads
    for (int i = t; i < H1 * H1 / 4; i += 256)
        ((float4*)slw1)[i] = ((const float4*)lw1)[i];
    for (int i = t; i < H1 * H2 / 4; i += 256)
        ((float4*)slw2)[i] = ((const float4*)lw2)[i];
    if (t < H2) slw3[t] = lw3[t];
    if (t < H1) sg[t] = g[t];
    __syncthreads();
    if (t < H1) {
        float a = lb1[t];
#pragma unroll 8
        for (int k = 0; k < H1; ++k) a = fmaf(sg[k], slw1[k * H1 + t], a);
        v1[t] = fmaxf(a, 0.0f);
    }
    __syncthreads();
    if (t < H2) {
        float a = lb2[t];
#pragma unroll 8
        for (int k = 0; k < H1; ++k) a = fmaf(v1[k], slw2[k * H2 + t], a);
        v2[t] = fmaxf(a, 0.0f);
    }
    __syncthreads();
    if (t == 0) {
        float a = lb3[0];
#pragma unroll 8
        for (int k = 0; k < H2; ++k) a = fmaf(v2[k], slw3[k], a);
        out[0] = a;
    }
}

extern "C" void kernel_launch(void* const* d_in, const int* in_sizes, int n_in,
                              void* d_out, int out_size, void* d_ws, size_t ws_size,
                              hipStream_t stream) {
    const float* x   = (const float*)d_in[0];
    const int*   ei  = (const int*)d_in[1];      // [2, N_EDGES] int32
    const float* W1  = (const float*)d_in[2];
    const float* b1  = (const float*)d_in[3];
    const float* lw1 = (const float*)d_in[4];
    const float* lb1 = (const float*)d_in[5];
    const float* lw2 = (const float*)d_in[6];
    const float* lb2 = (const float*)d_in[7];
    const float* lw3 = (const float*)d_in[8];
    const float* lb3 = (const float*)d_in[9];
    float* out = (float*)d_out;

    const int* src = ei;
    const int* dst = ei + N_EDGES;

    char* ws = (char*)d_ws;
    size_t off = 0;
    auto alloc = [&](size_t bytes) {
        char* p = ws + off;
        off = (off + bytes + 255) & ~(size_t)255;
        return p;
    };
    // deg and g contiguous so one memset clears both
    int*   deg        = (int*)alloc((size_t)N_NODES * sizeof(int));
    float* g          = (float*)alloc((size_t)H1 * sizeof(float));
    float* dinv       = (float*)alloc((size_t)N_NODES * sizeof(float));
    int*   row_start  = (int*)alloc((size_t)(N_NODES + 1) * sizeof(int));
    int*   cursor     = (int*)alloc((size_t)N_NODES * sizeof(int));
    int*   block_sums = (int*)alloc((size_t)N_SBLK * sizeof(int));
    int*   sorted_src = (int*)alloc((size_t)N_EDGES * sizeof(int));
    float* h          = (float*)alloc((size_t)N_NODES * H1 * sizeof(float));  // scaled in K3
    (void)ws_size;

    hipMemsetAsync(deg, 0, (char*)(g + H1) - (char*)deg, stream);

    // K1: gemm (h = x@W1, unscaled)  ||  degree histogram
    k1_gemm_count<<<GEMM_BLOCKS + COUNT_BLOCKS, 256, 0, stream>>>(x, W1, h, dst, deg);

    deg_part_kernel<<<N_SBLK, SCAN_BLK, 0, stream>>>(deg, block_sums);
    block_scan_kernel<<<1, SCAN_BLK, 0, stream>>>(block_sums);
    deg_scan_kernel<<<N_SBLK, SCAN_BLK, 0, stream>>>(deg, block_sums, row_start, cursor, dinv);

    // K3: CSR scatter  ||  h *= dinv[row]
    k3_scatter_scale<<<SCAT_BLOCKS + 512, 256, 0, stream>>>(src, dst, cursor, sorted_src, h, dinv);

    // agg in 3 range pieces (diagnostic split: surfaces prep dispatches >~35us in top-5)
    agg_pool_kernel<<<AGG_BLOCKS, 256, 0, stream>>>(h, row_start, sorted_src, dinv, b1, g,
                                                    0, N_THIRD);
    agg_pool_kernel<<<AGG_BLOCKS, 256, 0, stream>>>(h, row_start, sorted_src, dinv, b1, g,
                                                    N_THIRD, 2 * N_THIRD);
    agg_pool_kernel<<<AGG_BLOCKS, 256, 0, stream>>>(h, row_start, sorted_src, dinv, b1, g,
                                                    2 * N_THIRD, N_NODES);

    mlp_kernel<<<1, 256, 0, stream>>>(g, lw1, lb1, lw2, lb2, lw3, lb3, out);
}

// Round 13
// 226.701 us; speedup vs baseline: 1.6065x; 1.6065x over previous
//
#include <hip/hip_runtime.h>
#include <stdint.h>

#define N_NODES 50000
#define N_EDGES 800000
#define D_IN 128
#define H1 96
#define H2 64
#define GEMM_NODES 32
#define GEMM_BLOCKS ((N_NODES + GEMM_NODES - 1) / GEMM_NODES)  // 1563
#define SCAN_BLK 256
#define N_SBLK ((N_NODES + SCAN_BLK - 1) / SCAN_BLK)   // 196
#define SCAT_BLOCKS 2048
#define AGG_BLOCKS 2048

// dst-range owner: r(d) = d / 6250  (exact for d < 50000), ranges align with
// XCD via blockIdx&7 (round-robin dispatch).
__device__ __forceinline__ int xcd_range(int d) {
    return (int)(((unsigned long long)(unsigned)d * 687195ull) >> 32);
}

// ---------------- degree histogram, XCD-range-owned atomics ----------------
__global__ void count_deg_kernel(const int* __restrict__ dst, int* __restrict__ deg) {
    int r = blockIdx.x & 7;
    int gid = (blockIdx.x >> 3) * 256 + threadIdx.x;
    int stride = (SCAT_BLOCKS >> 3) * 256;  // 65536 per range-set
    const int4* d4 = (const int4*)dst;
    for (int i = gid; i < N_EDGES / 4; i += stride) {
        int4 d = d4[i];
        if (xcd_range(d.x) == r) atomicAdd(&deg[d.x], 1);
        if (xcd_range(d.y) == r) atomicAdd(&deg[d.y], 1);
        if (xcd_range(d.z) == r) atomicAdd(&deg[d.z], 1);
        if (xcd_range(d.w) == r) atomicAdd(&deg[d.w], 1);
    }
}

// ---------------- 3-phase device-wide exclusive scan ----------------
__global__ __launch_bounds__(SCAN_BLK) void deg_part_kernel(const int* __restrict__ deg,
                                                            int* __restrict__ block_sums) {
    __shared__ int s[SCAN_BLK];
    int t = threadIdx.x;
    int i = blockIdx.x * SCAN_BLK + t;
    s[t] = (i < N_NODES) ? deg[i] : 0;
    __syncthreads();
    for (int off = SCAN_BLK / 2; off > 0; off >>= 1) {
        if (t < off) s[t] += s[t + off];
        __syncthreads();
    }
    if (t == 0) block_sums[blockIdx.x] = s[0];
}

__global__ __launch_bounds__(SCAN_BLK) void block_scan_kernel(int* __restrict__ block_sums) {
    __shared__ int s[SCAN_BLK];
    int t = threadIdx.x;
    int v = (t < N_SBLK) ? block_sums[t] : 0;
    s[t] = v;
    __syncthreads();
    for (int off = 1; off < SCAN_BLK; off <<= 1) {
        int u = (t >= off) ? s[t - off] : 0;
        __syncthreads();
        s[t] += u;
        __syncthreads();
    }
    if (t < N_SBLK) block_sums[t] = s[t] - v;  // exclusive
}

__global__ __launch_bounds__(SCAN_BLK) void deg_scan_kernel(const int* __restrict__ deg,
                                                            const int* __restrict__ block_off,
                                                            int* __restrict__ row_start,
                                                            int* __restrict__ cursor,
                                                            float* __restrict__ dinv) {
    __shared__ int s[SCAN_BLK];
    int t = threadIdx.x;
    int i = blockIdx.x * SCAN_BLK + t;
    int v = (i < N_NODES) ? deg[i] : 0;
    s[t] = v;
    __syncthreads();
    for (int off = 1; off < SCAN_BLK; off <<= 1) {
        int u = (t >= off) ? s[t - off] : 0;
        __syncthreads();
        s[t] += u;
        __syncthreads();
    }
    int excl = s[t] - v + block_off[blockIdx.x];
    if (i < N_NODES) {
        row_start[i] = excl;
        cursor[i] = excl;
        dinv[i] = rsqrtf((float)v + 1.0f);  // +1 self-loop
    }
    if (i == 0) row_start[N_NODES] = N_EDGES;
}

// =============== K2: XCD-owned scatter (CSR)  ||  gemm hs = (x@W1)*dinv ===============
__global__ __launch_bounds__(256) void k2_scatter_gemm(const int* __restrict__ src,
                                                       const int* __restrict__ dst,
                                                       int* __restrict__ cursor,
                                                       int* __restrict__ sorted_src,
                                                       const float* __restrict__ x,
                                                       const float* __restrict__ W1,
                                                       const float* __restrict__ dinv,
                                                       float* __restrict__ hs) {
    __shared__ float sx[GEMM_NODES * D_IN];  // 16 KB
    int tid = threadIdx.x;

    if (blockIdx.x < SCAT_BLOCKS) {
        // scatter arm: range-set r owns dst in [r*6250, (r+1)*6250); its cursor
        // lines and sorted_src window (~400 KB) stay in ONE XCD's L2 -> full
        // lines on writeback, local atomics.
        int r = blockIdx.x & 7;
        int gid = (blockIdx.x >> 3) * 256 + tid;
        int stride = (SCAT_BLOCKS >> 3) * 256;  // 65536 per range-set
        const int4* s4p = (const int4*)src;
        const int4* d4p = (const int4*)dst;
        for (int i = gid; i < N_EDGES / 4; i += stride) {
            int4 sv = s4p[i];
            int4 dv = d4p[i];
            if (xcd_range(dv.x) == r) { int p = atomicAdd(&cursor[dv.x], 1); sorted_src[p] = sv.x; }
            if (xcd_range(dv.y) == r) { int p = atomicAdd(&cursor[dv.y], 1); sorted_src[p] = sv.y; }
            if (xcd_range(dv.z) == r) { int p = atomicAdd(&cursor[dv.z], 1); sorted_src[p] = sv.z; }
            if (xcd_range(dv.w) == r) { int p = atomicAdd(&cursor[dv.w], 1); sorted_src[p] = sv.w; }
        }
    } else {
        int gblk = blockIdx.x - SCAT_BLOCKS;
        int base = gblk * GEMM_NODES;
        const float4* x4 = (const float4*)x;
        for (int i = tid; i < GEMM_NODES * D_IN / 4; i += 256) {
            int n = base + i / (D_IN / 4);
            if (n < N_NODES) ((float4*)sx)[i] = x4[(size_t)base * (D_IN / 4) + i];
        }
        __syncthreads();

        int fg = tid & 31;
        int ng = tid >> 5;

        float acc[4][3];
#pragma unroll
        for (int i = 0; i < 4; ++i)
#pragma unroll
            for (int j = 0; j < 3; ++j) acc[i][j] = 0.0f;

#pragma unroll 4
        for (int k = 0; k < D_IN; ++k) {
            float w0 = W1[k * H1 + fg];
            float w1 = W1[k * H1 + fg + 32];
            float w2 = W1[k * H1 + fg + 64];
#pragma unroll
            for (int i = 0; i < 4; ++i) {
                float xv = sx[(ng * 4 + i) * D_IN + k];
                acc[i][0] = fmaf(xv, w0, acc[i][0]);
                acc[i][1] = fmaf(xv, w1, acc[i][1]);
                acc[i][2] = fmaf(xv, w2, acc[i][2]);
            }
        }

#pragma unroll
        for (int i = 0; i < 4; ++i) {
            int n = base + ng * 4 + i;
            if (n < N_NODES) {
                float dv = dinv[n];
                hs[(size_t)n * H1 + fg]      = acc[i][0] * dv;
                hs[(size_t)n * H1 + fg + 32] = acc[i][1] * dv;
                hs[(size_t)n * H1 + fg + 64] = acc[i][2] * dv;
            }
        }
    }
}

// ---------------- fused pull-aggregate + ReLU + sum-pool (R3-exact anchor) ----------------
__global__ __launch_bounds__(256) void agg_pool_kernel(const float* __restrict__ hs,
                                                       const int* __restrict__ row_start,
                                                       const int* __restrict__ sorted_src,
                                                       const float* __restrict__ dinv,
                                                       const float* __restrict__ b1,
                                                       float* __restrict__ g) {
    int tid = threadIdx.x;
    int grp = tid >> 7;
    int f = tid & 127;
    bool act = f < H1;
    float bf = act ? b1[f] : 0.0f;
    float gacc = 0.0f;

    for (int n = blockIdx.x * 2 + grp; n < N_NODES; n += gridDim.x * 2) {
        float acc = act ? hs[(size_t)n * H1 + f] : 0.0f;  // self-loop term
        int e = row_start[n];
        int eend = row_start[n + 1];
        for (; e + 4 <= eend; e += 4) {
            int s0 = sorted_src[e];
            int s1 = sorted_src[e + 1];
            int s2 = sorted_src[e + 2];
            int s3 = sorted_src[e + 3];
            if (act) {
                float v0 = hs[(size_t)s0 * H1 + f];
                float v1 = hs[(size_t)s1 * H1 + f];
                float v2 = hs[(size_t)s2 * H1 + f];
                float v3 = hs[(size_t)s3 * H1 + f];
                acc += (v0 + v1) + (v2 + v3);
            }
        }
        for (; e < eend; ++e) {
            int s = sorted_src[e];
            if (act) acc += hs[(size_t)s * H1 + f];
        }
        if (act) gacc += fmaxf(fmaf(dinv[n], acc, bf), 0.0f);
    }

    __shared__ float sg[H1];
    if (grp == 0 && act) sg[f] = gacc;
    __syncthreads();
    if (grp == 1 && act) atomicAdd(&sg[f], gacc);
    __syncthreads();
    if (grp == 0 && act) atomicAdd(&g[f], sg[f]);
}

// ---------------- tiny MLP head (weights staged in LDS, coalesced) ----------------
__global__ __launch_bounds__(256) void mlp_kernel(const float* __restrict__ g,
                           const float* __restrict__ lw1, const float* __restrict__ lb1,
                           const float* __restrict__ lw2, const float* __restrict__ lb2,
                           const float* __restrict__ lw3, const float* __restrict__ lb3,
                           float* __restrict__ out) {
    __shared__ float slw1[H1 * H1];  // 36 KB
    __shared__ float slw2[H1 * H2];  // 24 KB
    __shared__ float slw3[H2];
    __shared__ float sg[H1], v1[H1], v2[H2];
    int t = threadIdx.x;  // 256 threads
    for (int i = t; i < H1 * H1 / 4; i += 256)
        ((float4*)slw1)[i] = ((const float4*)lw1)[i];
    for (int i = t; i < H1 * H2 / 4; i += 256)
        ((float4*)slw2)[i] = ((const float4*)lw2)[i];
    if (t < H2) slw3[t] = lw3[t];
    if (t < H1) sg[t] = g[t];
    __syncthreads();
    if (t < H1) {
        float a = lb1[t];
#pragma unroll 8
        for (int k = 0; k < H1; ++k) a = fmaf(sg[k], slw1[k * H1 + t], a);
        v1[t] = fmaxf(a, 0.0f);
    }
    __syncthreads();
    if (t < H2) {
        float a = lb2[t];
#pragma unroll 8
        for (int k = 0; k < H1; ++k) a = fmaf(v1[k], slw2[k * H2 + t], a);
        v2[t] = fmaxf(a, 0.0f);
    }
    __syncthreads();
    if (t == 0) {
        float a = lb3[0];
#pragma unroll 8
        for (int k = 0; k < H2; ++k) a = fmaf(v2[k], slw3[k], a);
        out[0] = a;
    }
}

extern "C" void kernel_launch(void* const* d_in, const int* in_sizes, int n_in,
                              void* d_out, int out_size, void* d_ws, size_t ws_size,
                              hipStream_t stream) {
    const float* x   = (const float*)d_in[0];
    const int*   ei  = (const int*)d_in[1];      // [2, N_EDGES] int32
    const float* W1  = (const float*)d_in[2];
    const float* b1  = (const float*)d_in[3];
    const float* lw1 = (const float*)d_in[4];
    const float* lb1 = (const float*)d_in[5];
    const float* lw2 = (const float*)d_in[6];
    const float* lb2 = (const float*)d_in[7];
    const float* lw3 = (const float*)d_in[8];
    const float* lb3 = (const float*)d_in[9];
    float* out = (float*)d_out;

    const int* src = ei;
    const int* dst = ei + N_EDGES;

    char* ws = (char*)d_ws;
    size_t off = 0;
    auto alloc = [&](size_t bytes) {
        char* p = ws + off;
        off = (off + bytes + 255) & ~(size_t)255;
        return p;
    };
    // deg and g contiguous so one memset clears both
    int*   deg        = (int*)alloc((size_t)N_NODES * sizeof(int));
    float* g          = (float*)alloc((size_t)H1 * sizeof(float));
    float* dinv       = (float*)alloc((size_t)N_NODES * sizeof(float));
    int*   row_start  = (int*)alloc((size_t)(N_NODES + 1) * sizeof(int));
    int*   cursor     = (int*)alloc((size_t)N_NODES * sizeof(int));
    int*   block_sums = (int*)alloc((size_t)N_SBLK * sizeof(int));
    int*   sorted_src = (int*)alloc((size_t)N_EDGES * sizeof(int));
    float* hs         = (float*)alloc((size_t)N_NODES * H1 * sizeof(float));
    (void)ws_size;

    hipMemsetAsync(deg, 0, (char*)(g + H1) - (char*)deg, stream);

    count_deg_kernel<<<SCAT_BLOCKS, 256, 0, stream>>>(dst, deg);
    deg_part_kernel<<<N_SBLK, SCAN_BLK, 0, stream>>>(deg, block_sums);
    block_scan_kernel<<<1, SCAN_BLK, 0, stream>>>(block_sums);
    deg_scan_kernel<<<N_SBLK, SCAN_BLK, 0, stream>>>(deg, block_sums, row_start, cursor, dinv);

    // K2: XCD-owned CSR scatter  ||  hs = (x@W1)*dinv
    k2_scatter_gemm<<<SCAT_BLOCKS + GEMM_BLOCKS, 256, 0, stream>>>(src, dst, cursor, sorted_src,
                                                                   x, W1, dinv, hs);

    agg_pool_kernel<<<AGG_BLOCKS, 256, 0, stream>>>(hs, row_start, sorted_src, dinv, b1, g);

    mlp_kernel<<<1, 256, 0, stream>>>(g, lw1, lb1, lw2, lb2, lw3, lb3, out);
}

// Round 14
// 207.902 us; speedup vs baseline: 1.7517x; 1.0904x over previous
//
#include <hip/hip_runtime.h>
#include <stdint.h>

#define N_NODES 50000
#define N_EDGES 800000
#define D_IN 128
#define H1 96
#define H2 64
#define GEMM_NODES 32
#define GEMM_BLOCKS ((N_NODES + GEMM_NODES - 1) / GEMM_NODES)  // 1563
#define COUNT_BLOCKS 2048
#define SCAN_BLK 256
#define N_SBLK ((N_NODES + SCAN_BLK - 1) / SCAN_BLK)   // 196
#define SCAT_BLOCKS 2048
#define SCALE_BLOCKS 512
#define AGG_BLOCKS 2048

// dst-range owner: r(d) = d / 6250 (exact for d < 50000); aligns with XCD via
// blockIdx&7 (round-robin block->XCD dispatch).
__device__ __forceinline__ int xcd_range(int d) {
    return (int)(((unsigned long long)(unsigned)d * 687195ull) >> 32);
}

// =============== K1: gemm h = x@W1 (unscaled)  ||  XCD-owned count ===============
__global__ __launch_bounds__(256) void k1_gemm_count(const float* __restrict__ x,
                                                     const float* __restrict__ W1,
                                                     float* __restrict__ h,
                                                     const int* __restrict__ dst,
                                                     int* __restrict__ deg) {
    __shared__ float sx[GEMM_NODES * D_IN];  // 16 KB
    int tid = threadIdx.x;

    if (blockIdx.x < GEMM_BLOCKS) {
        int base = blockIdx.x * GEMM_NODES;
        const float4* x4 = (const float4*)x;
        for (int i = tid; i < GEMM_NODES * D_IN / 4; i += 256) {
            int n = base + i / (D_IN / 4);
            if (n < N_NODES) ((float4*)sx)[i] = x4[(size_t)base * (D_IN / 4) + i];
        }
        __syncthreads();

        int fg = tid & 31;
        int ng = tid >> 5;

        float acc[4][3];
#pragma unroll
        for (int i = 0; i < 4; ++i)
#pragma unroll
            for (int j = 0; j < 3; ++j) acc[i][j] = 0.0f;

#pragma unroll 4
        for (int k = 0; k < D_IN; ++k) {
            float w0 = W1[k * H1 + fg];
            float w1 = W1[k * H1 + fg + 32];
            float w2 = W1[k * H1 + fg + 64];
#pragma unroll
            for (int i = 0; i < 4; ++i) {
                float xv = sx[(ng * 4 + i) * D_IN + k];
                acc[i][0] = fmaf(xv, w0, acc[i][0]);
                acc[i][1] = fmaf(xv, w1, acc[i][1]);
                acc[i][2] = fmaf(xv, w2, acc[i][2]);
            }
        }

#pragma unroll
        for (int i = 0; i < 4; ++i) {
            int n = base + ng * 4 + i;
            if (n < N_NODES) {
                h[(size_t)n * H1 + fg]      = acc[i][0];
                h[(size_t)n * H1 + fg + 32] = acc[i][1];
                h[(size_t)n * H1 + fg + 64] = acc[i][2];
            }
        }
    } else {
        // XCD-owned count: r from GLOBAL blockIdx (physical XCD), local index
        // within the range-set from consecutive-8 grouping.
        int r = blockIdx.x & 7;
        int bid = blockIdx.x - GEMM_BLOCKS;
        int gid = (bid >> 3) * 256 + tid;
        int stride = (COUNT_BLOCKS >> 3) * 256;
        const int4* d4 = (const int4*)dst;
        for (int i = gid; i < N_EDGES / 4; i += stride) {
            int4 d = d4[i];
            if (xcd_range(d.x) == r) atomicAdd(&deg[d.x], 1);
            if (xcd_range(d.y) == r) atomicAdd(&deg[d.y], 1);
            if (xcd_range(d.z) == r) atomicAdd(&deg[d.z], 1);
            if (xcd_range(d.w) == r) atomicAdd(&deg[d.w], 1);
        }
    }
}

// ---------------- 3-phase device-wide exclusive scan ----------------
__global__ __launch_bounds__(SCAN_BLK) void deg_part_kernel(const int* __restrict__ deg,
                                                            int* __restrict__ block_sums) {
    __shared__ int s[SCAN_BLK];
    int t = threadIdx.x;
    int i = blockIdx.x * SCAN_BLK + t;
    s[t] = (i < N_NODES) ? deg[i] : 0;
    __syncthreads();
    for (int off = SCAN_BLK / 2; off > 0; off >>= 1) {
        if (t < off) s[t] += s[t + off];
        __syncthreads();
    }
    if (t == 0) block_sums[blockIdx.x] = s[0];
}

__global__ __launch_bounds__(SCAN_BLK) void block_scan_kernel(int* __restrict__ block_sums) {
    __shared__ int s[SCAN_BLK];
    int t = threadIdx.x;
    int v = (t < N_SBLK) ? block_sums[t] : 0;
    s[t] = v;
    __syncthreads();
    for (int off = 1; off < SCAN_BLK; off <<= 1) {
        int u = (t >= off) ? s[t - off] : 0;
        __syncthreads();
        s[t] += u;
        __syncthreads();
    }
    if (t < N_SBLK) block_sums[t] = s[t] - v;  // exclusive
}

__global__ __launch_bounds__(SCAN_BLK) void deg_scan_kernel(const int* __restrict__ deg,
                                                            const int* __restrict__ block_off,
                                                            int* __restrict__ row_start,
                                                            int* __restrict__ cursor,
                                                            float* __restrict__ dinv) {
    __shared__ int s[SCAN_BLK];
    int t = threadIdx.x;
    int i = blockIdx.x * SCAN_BLK + t;
    int v = (i < N_NODES) ? deg[i] : 0;
    s[t] = v;
    __syncthreads();
    for (int off = 1; off < SCAN_BLK; off <<= 1) {
        int u = (t >= off) ? s[t - off] : 0;
        __syncthreads();
        s[t] += u;
        __syncthreads();
    }
    int excl = s[t] - v + block_off[blockIdx.x];
    if (i < N_NODES) {
        row_start[i] = excl;
        cursor[i] = excl;
        dinv[i] = rsqrtf((float)v + 1.0f);  // +1 self-loop
    }
    if (i == 0) row_start[N_NODES] = N_EDGES;
}

// =============== K2: XCD-owned scatter (CSR)  ||  h *= dinv[row] ===============
__global__ __launch_bounds__(256) void k2_scatter_scale(const int* __restrict__ src,
                                                        const int* __restrict__ dst,
                                                        int* __restrict__ cursor,
                                                        int* __restrict__ sorted_src,
                                                        float* __restrict__ h,
                                                        const float* __restrict__ dinv) {
    int tid = threadIdx.x;
    if (blockIdx.x < SCAT_BLOCKS) {
        // range-set r owns dst in [r*6250,(r+1)*6250): cursor lines + ~400KB
        // sorted_src window stay in ONE XCD's L2 (plain stores -- keep cached).
        int r = blockIdx.x & 7;
        int gid = (blockIdx.x >> 3) * 256 + tid;
        int stride = (SCAT_BLOCKS >> 3) * 256;
        const int4* s4p = (const int4*)src;
        const int4* d4p = (const int4*)dst;
        for (int i = gid; i < N_EDGES / 4; i += stride) {
            int4 sv = s4p[i];
            int4 dv = d4p[i];
            if (xcd_range(dv.x) == r) { int p = atomicAdd(&cursor[dv.x], 1); sorted_src[p] = sv.x; }
            if (xcd_range(dv.y) == r) { int p = atomicAdd(&cursor[dv.y], 1); sorted_src[p] = sv.y; }
            if (xcd_range(dv.z) == r) { int p = atomicAdd(&cursor[dv.z], 1); sorted_src[p] = sv.z; }
            if (xcd_range(dv.w) == r) { int p = atomicAdd(&cursor[dv.w], 1); sorted_src[p] = sv.w; }
        }
    } else {
        // scale arm: h *= dinv[row]  (1.2M float4)
        int bid = blockIdx.x - SCAT_BLOCKS;
        int gid = bid * 256 + tid;
        int stride = SCALE_BLOCKS * 256;
        float4* h4 = (float4*)h;
        const int TOT = N_NODES * (H1 / 4);  // 1,200,000
        for (int i = gid; i < TOT; i += stride) {
            int n = i / (H1 / 4);
            float dv = dinv[n];
            float4 v = h4[i];
            v.x *= dv; v.y *= dv; v.z *= dv; v.w *= dv;
            h4[i] = v;
        }
    }
}

// ---------------- fused pull-aggregate + ReLU + sum-pool (R3-exact anchor) ----------------
__global__ __launch_bounds__(256) void agg_pool_kernel(const float* __restrict__ hs,
                                                       const int* __restrict__ row_start,
                                                       const int* __restrict__ sorted_src,
                                                       const float* __restrict__ dinv,
                                                       const float* __restrict__ b1,
                                                       float* __restrict__ g) {
    int tid = threadIdx.x;
    int grp = tid >> 7;
    int f = tid & 127;
    bool act = f < H1;
    float bf = act ? b1[f] : 0.0f;
    float gacc = 0.0f;

    for (int n = blockIdx.x * 2 + grp; n < N_NODES; n += gridDim.x * 2) {
        float acc = act ? hs[(size_t)n * H1 + f] : 0.0f;  // self-loop term
        int e = row_start[n];
        int eend = row_start[n + 1];
        for (; e + 4 <= eend; e += 4) {
            int s0 = sorted_src[e];
            int s1 = sorted_src[e + 1];
            int s2 = sorted_src[e + 2];
            int s3 = sorted_src[e + 3];
            if (act) {
                float v0 = hs[(size_t)s0 * H1 + f];
                float v1 = hs[(size_t)s1 * H1 + f];
                float v2 = hs[(size_t)s2 * H1 + f];
                float v3 = hs[(size_t)s3 * H1 + f];
                acc += (v0 + v1) + (v2 + v3);
            }
        }
        for (; e < eend; ++e) {
            int s = sorted_src[e];
            if (act) acc += hs[(size_t)s * H1 + f];
        }
        if (act) gacc += fmaxf(fmaf(dinv[n], acc, bf), 0.0f);
    }

    __shared__ float sg[H1];
    if (grp == 0 && act) sg[f] = gacc;
    __syncthreads();
    if (grp == 1 && act) atomicAdd(&sg[f], gacc);
    __syncthreads();
    if (grp == 0 && act) atomicAdd(&g[f], sg[f]);
}

// ---------------- tiny MLP head (weights staged in LDS, coalesced) ----------------
__global__ __launch_bounds__(256) void mlp_kernel(const float* __restrict__ g,
                           const float* __restrict__ lw1, const float* __restrict__ lb1,
                           const float* __restrict__ lw2, const float* __restrict__ lb2,
                           const float* __restrict__ lw3, const float* __restrict__ lb3,
                           float* __restrict__ out) {
    __shared__ float slw1[H1 * H1];  // 36 KB
    __shared__ float slw2[H1 * H2];  // 24 KB
    __shared__ float slw3[H2];
    __shared__ float sg[H1], v1[H1], v2[H2];
    int t = threadIdx.x;  // 256 threads
    for (int i = t; i < H1 * H1 / 4; i += 256)
        ((float4*)slw1)[i] = ((const float4*)lw1)[i];
    for (int i = t; i < H1 * H2 / 4; i += 256)
        ((float4*)slw2)[i] = ((const float4*)lw2)[i];
    if (t < H2) slw3[t] = lw3[t];
    if (t < H1) sg[t] = g[t];
    __syncthreads();
    if (t < H1) {
        float a = lb1[t];
#pragma unroll 8
        for (int k = 0; k < H1; ++k) a = fmaf(sg[k], slw1[k * H1 + t], a);
        v1[t] = fmaxf(a, 0.0f);
    }
    __syncthreads();
    if (t < H2) {
        float a = lb2[t];
#pragma unroll 8
        for (int k = 0; k < H1; ++k) a = fmaf(v1[k], slw2[k * H2 + t], a);
        v2[t] = fmaxf(a, 0.0f);
    }
    __syncthreads();
    if (t == 0) {
        float a = lb3[0];
#pragma unroll 8
        for (int k = 0; k < H2; ++k) a = fmaf(v2[k], slw3[k], a);
        out[0] = a;
    }
}

extern "C" void kernel_launch(void* const* d_in, const int* in_sizes, int n_in,
                              void* d_out, int out_size, void* d_ws, size_t ws_size,
                              hipStream_t stream) {
    const float* x   = (const float*)d_in[0];
    const int*   ei  = (const int*)d_in[1];      // [2, N_EDGES] int32
    const float* W1  = (const float*)d_in[2];
    const float* b1  = (const float*)d_in[3];
    const float* lw1 = (const float*)d_in[4];
    const float* lb1 = (const float*)d_in[5];
    const float* lw2 = (const float*)d_in[6];
    const float* lb2 = (const float*)d_in[7];
    const float* lw3 = (const float*)d_in[8];
    const float* lb3 = (const float*)d_in[9];
    float* out = (float*)d_out;

    const int* src = ei;
    const int* dst = ei + N_EDGES;

    char* ws = (char*)d_ws;
    size_t off = 0;
    auto alloc = [&](size_t bytes) {
        char* p = ws + off;
        off = (off + bytes + 255) & ~(size_t)255;
        return p;
    };
    // deg and g contiguous so one memset clears both
    int*   deg        = (int*)alloc((size_t)N_NODES * sizeof(int));
    float* g          = (float*)alloc((size_t)H1 * sizeof(float));
    float* dinv       = (float*)alloc((size_t)N_NODES * sizeof(float));
    int*   row_start  = (int*)alloc((size_t)(N_NODES + 1) * sizeof(int));
    int*   cursor     = (int*)alloc((size_t)N_NODES * sizeof(int));
    int*   block_sums = (int*)alloc((size_t)N_SBLK * sizeof(int));
    int*   sorted_src = (int*)alloc((size_t)N_EDGES * sizeof(int));
    float* h          = (float*)alloc((size_t)N_NODES * H1 * sizeof(float));  // scaled in K2
    (void)ws_size;

    hipMemsetAsync(deg, 0, (char*)(g + H1) - (char*)deg, stream);

    // K1: gemm (unscaled)  ||  XCD-owned degree histogram
    k1_gemm_count<<<GEMM_BLOCKS + COUNT_BLOCKS, 256, 0, stream>>>(x, W1, h, dst, deg);

    deg_part_kernel<<<N_SBLK, SCAN_BLK, 0, stream>>>(deg, block_sums);
    block_scan_kernel<<<1, SCAN_BLK, 0, stream>>>(block_sums);
    deg_scan_kernel<<<N_SBLK, SCAN_BLK, 0, stream>>>(deg, block_sums, row_start, cursor, dinv);

    // K2: XCD-owned CSR scatter  ||  h *= dinv[row]
    k2_scatter_scale<<<SCAT_BLOCKS + SCALE_BLOCKS, 256, 0, stream>>>(src, dst, cursor, sorted_src,
                                                                     h, dinv);

    agg_pool_kernel<<<AGG_BLOCKS, 256, 0, stream>>>(h, row_start, sorted_src, dinv, b1, g);

    mlp_kernel<<<1, 256, 0, stream>>>(g, lw1, lb1, lw2, lb2, lw3, lb3, out);
}